// Round 4
// baseline (1271.168 us; speedup 1.0000x reference)
//
#include <hip/hip_runtime.h>

#define PN 50000
#define PE 1600000
#define PB 4096
#define NW 8          // source windows
#define WSZ 6250      // window size (PN/NW)

typedef __attribute__((ext_vector_type(8))) short bf16x8;
typedef __attribute__((ext_vector_type(4))) float f32x4;

__device__ inline float b2f(ushort u) {
    union { unsigned int i; float f; } x; x.i = ((unsigned int)u) << 16; return x.f;
}
__device__ inline ushort f2b(float f) {
    union { float f; unsigned int i; } x; x.f = f;
    unsigned int r = (x.i + 0x7FFFu + ((x.i >> 16) & 1u)) >> 16;
    return (ushort)r;
}

// ---------------- workspace layout (in 4-byte words) ----------------
static constexpr size_t OFF_BN    = 0;                          // 256 f
static constexpr size_t OFF_TMPM  = 256;                        // 192*128
static constexpr size_t OFF_M     = OFF_TMPM + 192 * 128;       // 192*192
static constexpr size_t OFF_DEG2U = OFF_M + 192 * 192;          // 8N int (zeroed with DEG2D)
static constexpr size_t OFF_DEG2D = OFF_DEG2U + 8 * PN;         // 8N int
static constexpr size_t OFF_OFF2U = OFF_DEG2D + 8 * PN;         // 8N int (cursor -> end ptrs)
static constexpr size_t OFF_OFF2D = OFF_OFF2U + 8 * PN;         // 8N int
static constexpr size_t OFF_IDXU  = OFF_OFF2D + 8 * PN;         // E int
static constexpr size_t OFF_IDXD  = OFF_IDXU + PE;              // E int
static constexpr size_t OFF_WB16  = OFF_IDXD + PE;              // 43008 words
static constexpr size_t OFF_HB    = OFF_WB16 + 43008;           // N*192 bf16
static constexpr size_t OFF_PROJ  = OFF_HB + (size_t)PN * 96;   // N*192 bf16

// ---------------- batchnorm stats ----------------
__global__ __launch_bounds__(256) void bn_stats_kernel(const float* __restrict__ x,
                                                       float* __restrict__ sums, int N) {
    __shared__ float ls[256], ls2[256];
    int col = threadIdx.x & 63;
    int rstart = blockIdx.x * 4 + (threadIdx.x >> 6);
    float s = 0.f, s2 = 0.f;
    for (int r = rstart; r < N; r += gridDim.x * 4) {
        float v = x[(size_t)r * 64 + col];
        s += v; s2 += v * v;
    }
    ls[threadIdx.x] = s; ls2[threadIdx.x] = s2;
    __syncthreads();
    if (threadIdx.x < 64) {
        s  = ls[threadIdx.x]  + ls[threadIdx.x + 64]  + ls[threadIdx.x + 128]  + ls[threadIdx.x + 192];
        s2 = ls2[threadIdx.x] + ls2[threadIdx.x + 64] + ls2[threadIdx.x + 128] + ls2[threadIdx.x + 192];
        atomicAdd(&sums[col], s);
        atomicAdd(&sums[64 + col], s2);
    }
}

__global__ __launch_bounds__(64) void bn_finalize_kernel(const float* __restrict__ gamma,
                                                         const float* __restrict__ beta,
                                                         float* __restrict__ bn, int N) {
    int c = threadIdx.x;
    float mean = bn[c] / (float)N;
    float var = bn[64 + c] / (float)N - mean * mean;
    float sc = gamma[c] * rsqrtf(var + 1e-5f);
    bn[128 + c] = sc;
    bn[192 + c] = beta[c] - mean * sc;
}

// ---------------- CSR build (window-segmented) ----------------
__global__ __launch_bounds__(256) void deg_kernel(const int* __restrict__ ei,
                                                  int* __restrict__ deg2u,
                                                  int* __restrict__ deg2d, int E) {
    int e = blockIdx.x * 256 + threadIdx.x;
    if (e >= E) return;
    int r = __builtin_nontemporal_load(&ei[e]);
    int c = __builtin_nontemporal_load(&ei[E + e]);
    atomicAdd(&deg2u[c * NW + r / WSZ], 1);
    atomicAdd(&deg2d[r * NW + c / WSZ], 1);
}

// exclusive scan, 2 blocks (one per array), 4 elems/thread; len % 4 == 0
__global__ __launch_bounds__(1024) void scan_kernel(const int* __restrict__ degA,
                                                    const int* __restrict__ degB,
                                                    int* __restrict__ offA,
                                                    int* __restrict__ offB, int len) {
    const int* deg = blockIdx.x ? degB : degA;
    int* off = blockIdx.x ? offB : offA;
    __shared__ int wsum[17];
    int tid = threadIdx.x, lane = tid & 63, wid = tid >> 6;
    int run = 0;
    for (int base = 0; base < len; base += 4096) {
        int i4 = base + tid * 4;
        int4 v = make_int4(0, 0, 0, 0);
        if (i4 < len) v = *(const int4*)&deg[i4];
        int lsum = v.x + v.y + v.z + v.w;
        int inc = lsum;
#pragma unroll
        for (int d = 1; d < 64; d <<= 1) {
            int t = __shfl_up(inc, d);
            if (lane >= d) inc += t;
        }
        if (lane == 63) wsum[wid] = inc;
        __syncthreads();
        if (tid == 0) {
            int r2 = 0;
#pragma unroll
            for (int i = 0; i < 16; ++i) { int t = wsum[i]; wsum[i] = r2; r2 += t; }
            wsum[16] = r2;
        }
        __syncthreads();
        if (i4 < len) {
            int pre = run + wsum[wid] + inc - lsum;
            int4 o;
            o.x = pre; o.y = pre + v.x; o.z = o.y + v.y; o.w = o.z + v.z;
            *(int4*)&off[i4] = o;
        }
        run += wsum[16];
        __syncthreads();
    }
}

// per-direction fill; cur holds segment starts, mutated into end-pointers.
// partition p = blockIdx.x & 7 -> dest range [p*6250,(p+1)*6250) pinned per XCD.
template<bool UP>
__global__ __launch_bounds__(256) void fill_kernel(const int* __restrict__ ei,
                                                   int* __restrict__ cur,
                                                   int* __restrict__ idx, int E) {
    const int part = blockIdx.x & 7;
    const int slice = blockIdx.x >> 3;          // 64 slices
    const int lo = part * WSZ;
    const int hi = lo + WSZ;
    const int per = (E + 63) / 64;
    const int start = slice * per;
    const int end = min(E, start + per);
    for (int e = start + threadIdx.x; e < end; e += 256) {
        int r = __builtin_nontemporal_load(&ei[e]);
        int c = __builtin_nontemporal_load(&ei[E + e]);
        int dest = UP ? c : r;
        int src  = UP ? r : c;
        if (dest >= lo && dest < hi) {
            int pos = atomicAdd(&cur[dest * NW + src / WSZ], 1);
            idx[pos] = src;
        }
    }
}

// ---------------- weight convert ----------------
template<int K>
__global__ __launch_bounds__(256) void wconv_kernel(const float* __restrict__ Wu,
                                                    const float* __restrict__ Wd,
                                                    const float* __restrict__ Wb,
                                                    ushort* __restrict__ out) {
    int idx = blockIdx.x * 256 + threadIdx.x;
    if (idx >= 192 * K) return;
    int c = idx / K, k = idx - c * K;
    const float* W = (c < 64) ? Wu : (c < 128 ? Wd : Wb);
    out[idx] = f2b(W[k * 64 + (c & 63)]);
}

// ---------------- MFMA GEMM: proj[N,192] = A[N,K] @ W[K,192] ----------------
// 256 thr = 4 waves; block = 128 rows x 192 cols; each wave 2 row-tiles x 12 col-tiles
// (each B-frag LDS read feeds 2 MFMAs -> LDS/MFMA balanced).
// BN=true: layer 1, A = bn(x) computed inline from f32 x.
template<int K, bool BN>
__global__ __launch_bounds__(256) void gemm_kernel(const ushort* __restrict__ hb,
                                                   const float* __restrict__ x,
                                                   const float* __restrict__ bn,
                                                   const ushort* __restrict__ wb,
                                                   ushort* __restrict__ proj, int nrows) {
    constexpr int KP = K + 8;
    __shared__ ushort wlds[192 * KP];
    const int tid = threadIdx.x;
    constexpr int KB8 = K / 8;
    for (int idx = tid; idx < 192 * KB8; idx += 256) {
        int col = idx / KB8, kb = idx - col * KB8;
        *(bf16x8*)&wlds[col * KP + kb * 8] = *(const bf16x8*)&wb[(size_t)col * K + kb * 8];
    }
    __syncthreads();
    const int lane = tid & 63, wid = tid >> 6;
    const int kgrp = (lane >> 4) * 8;
    const int rbase = blockIdx.x * 128 + wid * 32;
    int ar[2] = { min(rbase + (lane & 15), nrows - 1),
                  min(rbase + 16 + (lane & 15), nrows - 1) };
    f32x4 acc[2][12];
#pragma unroll
    for (int rt = 0; rt < 2; ++rt)
#pragma unroll
        for (int ct = 0; ct < 12; ++ct) acc[rt][ct] = (f32x4)0.0f;

#pragma unroll
    for (int k0 = 0; k0 < K; k0 += 32) {
        bf16x8 af[2];
        if (BN) {
#pragma unroll
            for (int rt = 0; rt < 2; ++rt)
#pragma unroll
                for (int j = 0; j < 8; ++j) {
                    int c = k0 + kgrp + j;
                    float v = x[(size_t)ar[rt] * 64 + c] * bn[128 + c] + bn[192 + c];
                    af[rt][j] = (short)f2b(v);
                }
        } else {
#pragma unroll
            for (int rt = 0; rt < 2; ++rt)
                af[rt] = *(const bf16x8*)&hb[(size_t)ar[rt] * 192 + k0 + kgrp];
        }
#pragma unroll
        for (int ct = 0; ct < 12; ++ct) {
            bf16x8 bfr = *(const bf16x8*)&wlds[(ct * 16 + (lane & 15)) * KP + k0 + kgrp];
            acc[0][ct] = __builtin_amdgcn_mfma_f32_16x16x32_bf16(af[0], bfr, acc[0][ct], 0, 0, 0);
            acc[1][ct] = __builtin_amdgcn_mfma_f32_16x16x32_bf16(af[1], bfr, acc[1][ct], 0, 0, 0);
        }
    }
    const int orow0 = blockIdx.x * 128 + wid * 32 + (lane >> 4) * 4;
#pragma unroll
    for (int rt = 0; rt < 2; ++rt)
#pragma unroll
        for (int ct = 0; ct < 12; ++ct) {
            int ocol = ct * 16 + (lane & 15);
#pragma unroll
            for (int j = 0; j < 4; ++j) {
                int orow = orow0 + rt * 16 + j;
                if (orow < nrows) proj[(size_t)orow * 192 + ocol] = f2b(acc[rt][ct][j]);
            }
        }
}

// ---------------- fused gather (window-ordered) + normalize + leaky ----------------
// one wave per node; lane = feature; endu/endd are post-fill end-pointers.
__global__ __launch_bounds__(256) void gather_kernel(const ushort* __restrict__ proj,
                                                     const int* __restrict__ endu,
                                                     const int* __restrict__ idxu,
                                                     const int* __restrict__ endd,
                                                     const int* __restrict__ idxd,
                                                     ushort* __restrict__ hb, int N) {
    int n = blockIdx.x * 4 + (threadIdx.x >> 6);
    int lane = threadIdx.x & 63;
    if (n >= N) return;
    const int b = n * NW;
    float au = 0.f, ad = 0.f;
    int su = (n == 0) ? 0 : endu[b - 1];
    int sd = (n == 0) ? 0 : endd[b - 1];
    const int fu = su, fd = sd;
#pragma unroll 1
    for (int w = 0; w < NW; ++w) {
        int eu = endu[b + w];
        int i = su;
        for (; i + 4 <= eu; i += 4) {
            int s0 = idxu[i], s1 = idxu[i + 1], s2 = idxu[i + 2], s3 = idxu[i + 3];
            float v0 = b2f(proj[(size_t)s0 * 192 + lane]);
            float v1 = b2f(proj[(size_t)s1 * 192 + lane]);
            float v2 = b2f(proj[(size_t)s2 * 192 + lane]);
            float v3 = b2f(proj[(size_t)s3 * 192 + lane]);
            au += (v0 + v1) + (v2 + v3);
        }
        for (; i < eu; ++i) au += b2f(proj[(size_t)idxu[i] * 192 + lane]);
        su = eu;
        int ed = endd[b + w];
        i = sd;
        for (; i + 4 <= ed; i += 4) {
            int s0 = idxd[i], s1 = idxd[i + 1], s2 = idxd[i + 2], s3 = idxd[i + 3];
            float v0 = b2f(proj[(size_t)s0 * 192 + 64 + lane]);
            float v1 = b2f(proj[(size_t)s1 * 192 + 64 + lane]);
            float v2 = b2f(proj[(size_t)s2 * 192 + 64 + lane]);
            float v3 = b2f(proj[(size_t)s3 * 192 + 64 + lane]);
            ad += (v0 + v1) + (v2 + v3);
        }
        for (; i < ed; ++i) ad += b2f(proj[(size_t)idxd[i] * 192 + 64 + lane]);
        sd = ed;
    }
    au *= 1.0f / (float)max(su - fu, 1);
    ad *= 1.0f / (float)max(sd - fd, 1);
    float bi = b2f(proj[(size_t)n * 192 + 128 + lane]);
    float ss = au * au + ad * ad + bi * bi;
#pragma unroll
    for (int off = 32; off; off >>= 1) ss += __shfl_xor(ss, off);
    float r = 1.0f / fmaxf(sqrtf(ss), 1e-12f);
    au *= r; ad *= r; bi *= r;
    au = au >= 0.f ? au : 0.1f * au;
    ad = ad >= 0.f ? ad : 0.1f * ad;
    bi = bi >= 0.f ? bi : 0.1f * bi;
    hb[(size_t)n * 192 + lane] = f2b(au);
    hb[(size_t)n * 192 + 64 + lane] = f2b(ad);
    hb[(size_t)n * 192 + 128 + lane] = f2b(bi);
}

// ---------------- decoder ----------------
__global__ __launch_bounds__(128) void m1_kernel(const float* __restrict__ P1,
                                                 const float* __restrict__ P2,
                                                 float* __restrict__ tmpM) {
    int i = blockIdx.x, c = threadIdx.x;
    float s = 0.f;
    for (int k = 0; k < 128; ++k) s += P1[i * 128 + k] * P2[k * 128 + c];
    tmpM[i * 128 + c] = s;
}

__global__ __launch_bounds__(192) void m2_kernel(const float* __restrict__ tmpM,
                                                 const float* __restrict__ P1,
                                                 float* __restrict__ M) {
    __shared__ float trow[128];
    int i = blockIdx.x, j = threadIdx.x;
    if (j < 128) trow[j] = tmpM[i * 128 + j];
    __syncthreads();
    float s = 0.f;
    for (int k = 0; k < 128; ++k) s += trow[k] * P1[j * 128 + k];
    M[i * 192 + j] = s;
}

__global__ __launch_bounds__(192) void decode_kernel(const ushort* __restrict__ hb,
                                                     const int* __restrict__ di,
                                                     const float* __restrict__ M,
                                                     float* __restrict__ out) {
    __shared__ alignas(16) float bvs[8][192];
    __shared__ float red[3][8];
    int pb = blockIdx.x * 8;
    int i = threadIdx.x;
#pragma unroll
    for (int p = 0; p < 8; ++p) {
        int nb = di[(pb + p) * 2 + 1] - 1;
        bvs[p][i] = b2f(hb[(size_t)nb * 192 + i]);
    }
    __syncthreads();
    float t[8] = {};
    const float4* M4 = (const float4*)(M + (size_t)i * 192);
    for (int j4 = 0; j4 < 48; ++j4) {
        float4 m = M4[j4];
#pragma unroll
        for (int p = 0; p < 8; ++p) {
            float4 b = *(const float4*)&bvs[p][j4 * 4];
            t[p] += m.x * b.x + m.y * b.y + m.z * b.z + m.w * b.w;
        }
    }
    int wid = i >> 6, lane = i & 63;
#pragma unroll
    for (int p = 0; p < 8; ++p) {
        int na = di[(pb + p) * 2] - 1;
        float v = b2f(hb[(size_t)na * 192 + i]) * t[p];
#pragma unroll
        for (int off = 32; off; off >>= 1) v += __shfl_xor(v, off);
        if (lane == 0) red[wid][p] = v;
    }
    __syncthreads();
    if (i < 8) out[pb + i] = red[0][i] + red[1][i] + red[2][i];
}

extern "C" void kernel_launch(void* const* d_in, const int* in_sizes, int n_in,
                              void* d_out, int out_size, void* d_ws, size_t ws_size,
                              hipStream_t stream) {
    const float* x     = (const float*)d_in[0];
    const int*   ei    = (const int*)d_in[1];
    const int*   di    = (const int*)d_in[2];
    const float* gamma = (const float*)d_in[3];
    const float* beta  = (const float*)d_in[4];
    const float* Wu[3] = {(const float*)d_in[5], (const float*)d_in[8],  (const float*)d_in[11]};
    const float* Wd[3] = {(const float*)d_in[6], (const float*)d_in[9],  (const float*)d_in[12]};
    const float* Wb[3] = {(const float*)d_in[7], (const float*)d_in[10], (const float*)d_in[13]};
    const float* P1    = (const float*)d_in[14];
    const float* P2    = (const float*)d_in[15];
    float* out = (float*)d_out;
    float* ws  = (float*)d_ws;

    float* bn    = ws + OFF_BN;
    float* tmpM  = ws + OFF_TMPM;
    float* M     = ws + OFF_M;
    int* deg2u = (int*)(ws + OFF_DEG2U);
    int* deg2d = (int*)(ws + OFF_DEG2D);
    int* off2u = (int*)(ws + OFF_OFF2U);
    int* off2d = (int*)(ws + OFF_OFF2D);
    int* idxu  = (int*)(ws + OFF_IDXU);
    int* idxd  = (int*)(ws + OFF_IDXD);
    ushort* wb16 = (ushort*)(ws + OFF_WB16);
    ushort* hb   = (ushort*)(ws + OFF_HB);
    ushort* proj = (ushort*)(ws + OFF_PROJ);
    ushort* wbl[3] = {wb16, wb16 + 12288, wb16 + 49152};

    hipMemsetAsync(bn, 0, 128 * sizeof(float), stream);
    hipMemsetAsync(deg2u, 0, 2 * 8 * (size_t)PN * sizeof(int), stream);  // deg2u|deg2d

    bn_stats_kernel<<<200, 256, 0, stream>>>(x, bn, PN);
    bn_finalize_kernel<<<1, 64, 0, stream>>>(gamma, beta, bn, PN);

    deg_kernel<<<(PE + 255) / 256, 256, 0, stream>>>(ei, deg2u, deg2d, PE);
    scan_kernel<<<2, 1024, 0, stream>>>(deg2u, deg2d, off2u, off2d, NW * PN);
    fill_kernel<true><<<8 * 64, 256, 0, stream>>>(ei, off2u, idxu, PE);
    fill_kernel<false><<<8 * 64, 256, 0, stream>>>(ei, off2d, idxd, PE);

    wconv_kernel<64><<<(192 * 64 + 255) / 256, 256, 0, stream>>>(Wu[0], Wd[0], Wb[0], wbl[0]);
    wconv_kernel<192><<<(192 * 192 + 255) / 256, 256, 0, stream>>>(Wu[1], Wd[1], Wb[1], wbl[1]);
    wconv_kernel<192><<<(192 * 192 + 255) / 256, 256, 0, stream>>>(Wu[2], Wd[2], Wb[2], wbl[2]);

    const int ngb = (PN + 127) / 128;
    gemm_kernel<64, true><<<ngb, 256, 0, stream>>>(hb, x, bn, wbl[0], proj, PN);
    gather_kernel<<<(PN + 3) / 4, 256, 0, stream>>>(proj, off2u, idxu, off2d, idxd, hb, PN);
    gemm_kernel<192, false><<<ngb, 256, 0, stream>>>(hb, x, bn, wbl[1], proj, PN);
    gather_kernel<<<(PN + 3) / 4, 256, 0, stream>>>(proj, off2u, idxu, off2d, idxd, hb, PN);
    gemm_kernel<192, false><<<ngb, 256, 0, stream>>>(hb, x, bn, wbl[2], proj, PN);
    gather_kernel<<<(PN + 3) / 4, 256, 0, stream>>>(proj, off2u, idxu, off2d, idxd, hb, PN);

    m1_kernel<<<192, 128, 0, stream>>>(P1, P2, tmpM);
    m2_kernel<<<192, 192, 0, stream>>>(tmpM, P1, M);
    decode_kernel<<<PB / 8, 192, 0, stream>>>(hb, di, M, out);
}

// Round 6
// 799.772 us; speedup vs baseline: 1.5894x; 1.5894x over previous
//
#include <hip/hip_runtime.h>

#define PN 50000
#define PE 1600000
#define PB 4096

typedef __attribute__((ext_vector_type(8))) short bf16x8;
typedef __attribute__((ext_vector_type(4))) float f32x4;

__device__ inline float b2f(ushort u) {
    union { unsigned int i; float f; } x; x.i = ((unsigned int)u) << 16; return x.f;
}
__device__ inline ushort f2b(float f) {
    union { float f; unsigned int i; } x; x.f = f;
    unsigned int r = (x.i + 0x7FFFu + ((x.i >> 16) & 1u)) >> 16;
    return (ushort)r;
}

// ---------------- workspace layout (in 4-byte words) ----------------
// idx arrays are ushort; padded segment capacity E + 7N entries each.
static constexpr size_t IDXCAP = PE + 7 * PN;                  // ushort entries
static constexpr size_t OFF_BN    = 0;                          // 256 f
static constexpr size_t OFF_TMPM  = 256;                        // 192*128
static constexpr size_t OFF_M     = OFF_TMPM + 192 * 128;       // 192*192
static constexpr size_t OFF_DEGU  = OFF_M + 192 * 192;          // N int  (zeroed 4N block)
static constexpr size_t OFF_DEGD  = OFF_DEGU + PN;              // N int
static constexpr size_t OFF_CURU  = OFF_DEGD + PN;              // N int
static constexpr size_t OFF_CURD  = OFF_CURU + PN;              // N int
static constexpr size_t OFF_OFFU  = OFF_CURD + PN;              // N+1 int
static constexpr size_t OFF_OFFD  = OFF_OFFU + PN + 1;          // N+1 int
static constexpr size_t OFF_IDXU  = OFF_OFFD + PN + 1;          // IDXCAP ushort
static constexpr size_t OFF_IDXD  = OFF_IDXU + (IDXCAP + 1) / 2;
static constexpr size_t OFF_WB16  = OFF_IDXD + (IDXCAP + 1) / 2;// 43008 words
static constexpr size_t OFF_HB    = OFF_WB16 + 43008;           // N*192 bf16
static constexpr size_t OFF_PROJ  = OFF_HB + (size_t)PN * 96;   // N*192 bf16

// ---------------- batchnorm stats ----------------
__global__ __launch_bounds__(256) void bn_stats_kernel(const float* __restrict__ x,
                                                       float* __restrict__ sums, int N) {
    __shared__ float ls[256], ls2[256];
    int col = threadIdx.x & 63;
    int rstart = blockIdx.x * 4 + (threadIdx.x >> 6);
    float s = 0.f, s2 = 0.f;
    for (int r = rstart; r < N; r += gridDim.x * 4) {
        float v = x[(size_t)r * 64 + col];
        s += v; s2 += v * v;
    }
    ls[threadIdx.x] = s; ls2[threadIdx.x] = s2;
    __syncthreads();
    if (threadIdx.x < 64) {
        s  = ls[threadIdx.x]  + ls[threadIdx.x + 64]  + ls[threadIdx.x + 128]  + ls[threadIdx.x + 192];
        s2 = ls2[threadIdx.x] + ls2[threadIdx.x + 64] + ls2[threadIdx.x + 128] + ls2[threadIdx.x + 192];
        atomicAdd(&sums[col], s);
        atomicAdd(&sums[64 + col], s2);
    }
}

__global__ __launch_bounds__(64) void bn_finalize_kernel(const float* __restrict__ gamma,
                                                         const float* __restrict__ beta,
                                                         float* __restrict__ bn, int N) {
    int c = threadIdx.x;
    float mean = bn[c] / (float)N;
    float var = bn[64 + c] / (float)N - mean * mean;
    float sc = gamma[c] * rsqrtf(var + 1e-5f);
    bn[128 + c] = sc;
    bn[192 + c] = beta[c] - mean * sc;
}

// ---------------- CSR build ----------------
__global__ __launch_bounds__(256) void deg_kernel(const int* __restrict__ ei,
                                                  int* __restrict__ degu,
                                                  int* __restrict__ degd, int E) {
    int e = blockIdx.x * 256 + threadIdx.x;
    if (e >= E) return;
    atomicAdd(&degu[ei[E + e]], 1);
    atomicAdd(&degd[ei[e]], 1);
}

// exclusive scan of PADDED degrees ((d+7)&~7); 2 blocks, 4 elems/thread.
__global__ __launch_bounds__(1024) void scan_kernel(const int* __restrict__ degA,
                                                    const int* __restrict__ degB,
                                                    int* __restrict__ offA,
                                                    int* __restrict__ offB, int len) {
    const int* deg = blockIdx.x ? degB : degA;
    int* off = blockIdx.x ? offB : offA;
    __shared__ int wsum[17];
    int tid = threadIdx.x, lane = tid & 63, wid = tid >> 6;
    int run = 0;
    for (int base = 0; base < len; base += 4096) {
        int i4 = base + tid * 4;
        int4 v = make_int4(0, 0, 0, 0);
        if (i4 < len) v = *(const int4*)&deg[i4];
        v.x = (v.x + 7) & ~7; v.y = (v.y + 7) & ~7;
        v.z = (v.z + 7) & ~7; v.w = (v.w + 7) & ~7;
        int lsum = v.x + v.y + v.z + v.w;
        int inc = lsum;
#pragma unroll
        for (int d = 1; d < 64; d <<= 1) {
            int t = __shfl_up(inc, d);
            if (lane >= d) inc += t;
        }
        if (lane == 63) wsum[wid] = inc;
        __syncthreads();
        if (tid == 0) {
            int r2 = 0;
#pragma unroll
            for (int i = 0; i < 16; ++i) { int t = wsum[i]; wsum[i] = r2; r2 += t; }
            wsum[16] = r2;
        }
        __syncthreads();
        if (i4 < len) {
            int pre = run + wsum[wid] + inc - lsum;
            int4 o;
            o.x = pre; o.y = pre + v.x; o.z = o.y + v.y; o.w = o.z + v.z;
            *(int4*)&off[i4] = o;
        }
        run += wsum[16];
        __syncthreads();
    }
    if (tid == 0) off[len] = run;
}

// combined fill, XCD-partitioned: part = blockIdx.x & 7 owns dest range.
__global__ __launch_bounds__(256) void fill_kernel(const int* __restrict__ ei,
                                                   const int* __restrict__ offu,
                                                   const int* __restrict__ offd,
                                                   int* __restrict__ curu,
                                                   int* __restrict__ curd,
                                                   ushort* __restrict__ idxu,
                                                   ushort* __restrict__ idxd, int E) {
    const int part = blockIdx.x & 7;
    const int slice = blockIdx.x >> 3;          // 64 slices
    const int lo = part * (PN / 8);
    const int hi = lo + (PN / 8);
    const int per = (E + 63) / 64;
    const int start = slice * per;
    const int end = min(E, start + per);
    for (int e = start + threadIdx.x; e < end; e += 256) {
        int r = ei[e], c = ei[E + e];
        if (c >= lo && c < hi) {
            int pos = atomicAdd(&curu[c], 1);
            idxu[offu[c] + pos] = (ushort)r;
        }
        if (r >= lo && r < hi) {
            int pos = atomicAdd(&curd[r], 1);
            idxd[offd[r] + pos] = (ushort)c;
        }
    }
}

// ---------------- weight convert ----------------
template<int K>
__global__ __launch_bounds__(256) void wconv_kernel(const float* __restrict__ Wu,
                                                    const float* __restrict__ Wd,
                                                    const float* __restrict__ Wb,
                                                    ushort* __restrict__ out) {
    int idx = blockIdx.x * 256 + threadIdx.x;
    if (idx >= 192 * K) return;
    int c = idx / K, k = idx - c * K;
    const float* W = (c < 64) ? Wu : (c < 128 ? Wd : Wb);
    out[idx] = f2b(W[k * 64 + (c & 63)]);
}

// ---------------- MFMA GEMM: proj[N,192] = A[N,K] @ W[K,192] ----------------
template<int K, bool BN>
__global__ __launch_bounds__(256) void gemm_kernel(const ushort* __restrict__ hb,
                                                   const float* __restrict__ x,
                                                   const float* __restrict__ bn,
                                                   const ushort* __restrict__ wb,
                                                   ushort* __restrict__ proj, int nrows) {
    constexpr int KP = K + 8;
    __shared__ ushort wlds[192 * KP];
    const int tid = threadIdx.x;
    constexpr int KB8 = K / 8;
    for (int idx = tid; idx < 192 * KB8; idx += 256) {
        int col = idx / KB8, kb = idx - col * KB8;
        *(bf16x8*)&wlds[col * KP + kb * 8] = *(const bf16x8*)&wb[(size_t)col * K + kb * 8];
    }
    __syncthreads();
    const int lane = tid & 63, wid = tid >> 6;
    const int kgrp = (lane >> 4) * 8;
    const int rbase = blockIdx.x * 128 + wid * 32;
    int ar[2] = { min(rbase + (lane & 15), nrows - 1),
                  min(rbase + 16 + (lane & 15), nrows - 1) };
    f32x4 acc[2][12];
#pragma unroll
    for (int rt = 0; rt < 2; ++rt)
#pragma unroll
        for (int ct = 0; ct < 12; ++ct) acc[rt][ct] = (f32x4)0.0f;

#pragma unroll
    for (int k0 = 0; k0 < K; k0 += 32) {
        bf16x8 af[2];
        if (BN) {
#pragma unroll
            for (int rt = 0; rt < 2; ++rt)
#pragma unroll
                for (int j = 0; j < 8; ++j) {
                    int c = k0 + kgrp + j;
                    float v = x[(size_t)ar[rt] * 64 + c] * bn[128 + c] + bn[192 + c];
                    af[rt][j] = (short)f2b(v);
                }
        } else {
#pragma unroll
            for (int rt = 0; rt < 2; ++rt)
                af[rt] = *(const bf16x8*)&hb[(size_t)ar[rt] * 192 + k0 + kgrp];
        }
#pragma unroll
        for (int ct = 0; ct < 12; ++ct) {
            bf16x8 bfr = *(const bf16x8*)&wlds[(ct * 16 + (lane & 15)) * KP + k0 + kgrp];
            acc[0][ct] = __builtin_amdgcn_mfma_f32_16x16x32_bf16(af[0], bfr, acc[0][ct], 0, 0, 0);
            acc[1][ct] = __builtin_amdgcn_mfma_f32_16x16x32_bf16(af[1], bfr, acc[1][ct], 0, 0, 0);
        }
    }
    const int orow0 = blockIdx.x * 128 + wid * 32 + (lane >> 4) * 4;
#pragma unroll
    for (int rt = 0; rt < 2; ++rt)
#pragma unroll
        for (int ct = 0; ct < 12; ++ct) {
            int ocol = ct * 16 + (lane & 15);
#pragma unroll
            for (int j = 0; j < 4; ++j) {
                int orow = orow0 + rt * 16 + j;
                if (orow < nrows) proj[(size_t)orow * 192 + ocol] = f2b(acc[rt][ct][j]);
            }
        }
}

// ---------------- fused gather + normalize + leaky ----------------
// one wave per node; lane = feature; joint up/dn unroll for 8 loads in flight.
__global__ __launch_bounds__(256) void gather_kernel(const ushort* __restrict__ proj,
                                                     const int* __restrict__ offu,
                                                     const ushort* __restrict__ idxu,
                                                     const int* __restrict__ degu,
                                                     const int* __restrict__ offd,
                                                     const ushort* __restrict__ idxd,
                                                     const int* __restrict__ degd,
                                                     ushort* __restrict__ hb, int N) {
    int n = blockIdx.x * 4 + (threadIdx.x >> 6);
    int lane = threadIdx.x & 63;
    if (n >= N) return;
    const int du = degu[n], dd = degd[n];
    const ushort* __restrict__ pu = idxu + offu[n];
    const ushort* __restrict__ pd = idxd + offd[n];
    const ushort* __restrict__ ru = proj + lane;        // up rows
    const ushort* __restrict__ rd = proj + 64 + lane;   // dn rows
    float au = 0.f, ad = 0.f;
    int iu = 0, id = 0;
    while (iu + 4 <= du && id + 4 <= dd) {
        ushort4 U = *(const ushort4*)(pu + iu);
        ushort4 D = *(const ushort4*)(pd + id);
        float u0 = b2f(ru[(size_t)U.x * 192]);
        float u1 = b2f(ru[(size_t)U.y * 192]);
        float u2 = b2f(ru[(size_t)U.z * 192]);
        float u3 = b2f(ru[(size_t)U.w * 192]);
        float d0 = b2f(rd[(size_t)D.x * 192]);
        float d1 = b2f(rd[(size_t)D.y * 192]);
        float d2 = b2f(rd[(size_t)D.z * 192]);
        float d3 = b2f(rd[(size_t)D.w * 192]);
        au += (u0 + u1) + (u2 + u3);
        ad += (d0 + d1) + (d2 + d3);
        iu += 4; id += 4;
    }
    while (iu + 4 <= du) {
        ushort4 U = *(const ushort4*)(pu + iu);
        float u0 = b2f(ru[(size_t)U.x * 192]);
        float u1 = b2f(ru[(size_t)U.y * 192]);
        float u2 = b2f(ru[(size_t)U.z * 192]);
        float u3 = b2f(ru[(size_t)U.w * 192]);
        au += (u0 + u1) + (u2 + u3);
        iu += 4;
    }
    while (id + 4 <= dd) {
        ushort4 D = *(const ushort4*)(pd + id);
        float d0 = b2f(rd[(size_t)D.x * 192]);
        float d1 = b2f(rd[(size_t)D.y * 192]);
        float d2 = b2f(rd[(size_t)D.z * 192]);
        float d3 = b2f(rd[(size_t)D.w * 192]);
        ad += (d0 + d1) + (d2 + d3);
        id += 4;
    }
    for (; iu < du; ++iu) au += b2f(ru[(size_t)pu[iu] * 192]);
    for (; id < dd; ++id) ad += b2f(rd[(size_t)pd[id] * 192]);

    au *= 1.0f / (float)max(du, 1);
    ad *= 1.0f / (float)max(dd, 1);
    float bi = b2f(proj[(size_t)n * 192 + 128 + lane]);
    float ss = au * au + ad * ad + bi * bi;
#pragma unroll
    for (int off = 32; off; off >>= 1) ss += __shfl_xor(ss, off);
    float r = 1.0f / fmaxf(sqrtf(ss), 1e-12f);
    au *= r; ad *= r; bi *= r;
    au = au >= 0.f ? au : 0.1f * au;
    ad = ad >= 0.f ? ad : 0.1f * ad;
    bi = bi >= 0.f ? bi : 0.1f * bi;
    hb[(size_t)n * 192 + lane] = f2b(au);
    hb[(size_t)n * 192 + 64 + lane] = f2b(ad);
    hb[(size_t)n * 192 + 128 + lane] = f2b(bi);
}

// ---------------- decoder ----------------
__global__ __launch_bounds__(128) void m1_kernel(const float* __restrict__ P1,
                                                 const float* __restrict__ P2,
                                                 float* __restrict__ tmpM) {
    int i = blockIdx.x, c = threadIdx.x;
    float s = 0.f;
    for (int k = 0; k < 128; ++k) s += P1[i * 128 + k] * P2[k * 128 + c];
    tmpM[i * 128 + c] = s;
}

__global__ __launch_bounds__(192) void m2_kernel(const float* __restrict__ tmpM,
                                                 const float* __restrict__ P1,
                                                 float* __restrict__ M) {
    __shared__ float trow[128];
    int i = blockIdx.x, j = threadIdx.x;
    if (j < 128) trow[j] = tmpM[i * 128 + j];
    __syncthreads();
    float s = 0.f;
    for (int k = 0; k < 128; ++k) s += trow[k] * P1[j * 128 + k];
    M[i * 192 + j] = s;
}

__global__ __launch_bounds__(192) void decode_kernel(const ushort* __restrict__ hb,
                                                     const int* __restrict__ di,
                                                     const float* __restrict__ M,
                                                     float* __restrict__ out) {
    __shared__ alignas(16) float bvs[8][192];
    __shared__ float red[3][8];
    int pb = blockIdx.x * 8;
    int i = threadIdx.x;
#pragma unroll
    for (int p = 0; p < 8; ++p) {
        int nb = di[(pb + p) * 2 + 1] - 1;
        bvs[p][i] = b2f(hb[(size_t)nb * 192 + i]);
    }
    __syncthreads();
    float t[8] = {};
    const float4* M4 = (const float4*)(M + (size_t)i * 192);
    for (int j4 = 0; j4 < 48; ++j4) {
        float4 m = M4[j4];
#pragma unroll
        for (int p = 0; p < 8; ++p) {
            float4 b = *(const float4*)&bvs[p][j4 * 4];
            t[p] += m.x * b.x + m.y * b.y + m.z * b.z + m.w * b.w;
        }
    }
    int wid = i >> 6, lane = i & 63;
#pragma unroll
    for (int p = 0; p < 8; ++p) {
        int na = di[(pb + p) * 2] - 1;
        float v = b2f(hb[(size_t)na * 192 + i]) * t[p];
#pragma unroll
        for (int off = 32; off; off >>= 1) v += __shfl_xor(v, off);
        if (lane == 0) red[wid][p] = v;
    }
    __syncthreads();
    if (i < 8) out[pb + i] = red[0][i] + red[1][i] + red[2][i];
}

extern "C" void kernel_launch(void* const* d_in, const int* in_sizes, int n_in,
                              void* d_out, int out_size, void* d_ws, size_t ws_size,
                              hipStream_t stream) {
    const float* x     = (const float*)d_in[0];
    const int*   ei    = (const int*)d_in[1];
    const int*   di    = (const int*)d_in[2];
    const float* gamma = (const float*)d_in[3];
    const float* beta  = (const float*)d_in[4];
    const float* Wu[3] = {(const float*)d_in[5], (const float*)d_in[8],  (const float*)d_in[11]};
    const float* Wd[3] = {(const float*)d_in[6], (const float*)d_in[9],  (const float*)d_in[12]};
    const float* Wb[3] = {(const float*)d_in[7], (const float*)d_in[10], (const float*)d_in[13]};
    const float* P1    = (const float*)d_in[14];
    const float* P2    = (const float*)d_in[15];
    float* out = (float*)d_out;
    float* ws  = (float*)d_ws;

    float* bn    = ws + OFF_BN;
    float* tmpM  = ws + OFF_TMPM;
    float* M     = ws + OFF_M;
    int* degu = (int*)(ws + OFF_DEGU);
    int* degd = (int*)(ws + OFF_DEGD);
    int* curu = (int*)(ws + OFF_CURU);
    int* curd = (int*)(ws + OFF_CURD);
    int* offu = (int*)(ws + OFF_OFFU);
    int* offd = (int*)(ws + OFF_OFFD);
    ushort* idxu = (ushort*)(ws + OFF_IDXU);
    ushort* idxd = (ushort*)(ws + OFF_IDXD);
    ushort* wb16 = (ushort*)(ws + OFF_WB16);
    ushort* hb   = (ushort*)(ws + OFF_HB);
    ushort* proj = (ushort*)(ws + OFF_PROJ);
    ushort* wbl[3] = {wb16, wb16 + 12288, wb16 + 49152};

    hipMemsetAsync(bn, 0, 128 * sizeof(float), stream);
    hipMemsetAsync(degu, 0, 4 * (size_t)PN * sizeof(int), stream);  // degu|degd|curu|curd

    bn_stats_kernel<<<200, 256, 0, stream>>>(x, bn, PN);
    bn_finalize_kernel<<<1, 64, 0, stream>>>(gamma, beta, bn, PN);

    deg_kernel<<<(PE + 255) / 256, 256, 0, stream>>>(ei, degu, degd, PE);
    scan_kernel<<<2, 1024, 0, stream>>>(degu, degd, offu, offd, PN);
    fill_kernel<<<8 * 64, 256, 0, stream>>>(ei, offu, offd, curu, curd, idxu, idxd, PE);

    wconv_kernel<64><<<(192 * 64 + 255) / 256, 256, 0, stream>>>(Wu[0], Wd[0], Wb[0], wbl[0]);
    wconv_kernel<192><<<(192 * 192 + 255) / 256, 256, 0, stream>>>(Wu[1], Wd[1], Wb[1], wbl[1]);
    wconv_kernel<192><<<(192 * 192 + 255) / 256, 256, 0, stream>>>(Wu[2], Wd[2], Wb[2], wbl[2]);

    const int ngb = (PN + 127) / 128;
    gemm_kernel<64, true><<<ngb, 256, 0, stream>>>(hb, x, bn, wbl[0], proj, PN);
    gather_kernel<<<(PN + 3) / 4, 256, 0, stream>>>(proj, offu, idxu, degu, offd, idxd, degd, hb, PN);
    gemm_kernel<192, false><<<ngb, 256, 0, stream>>>(hb, x, bn, wbl[1], proj, PN);
    gather_kernel<<<(PN + 3) / 4, 256, 0, stream>>>(proj, offu, idxu, degu, offd, idxd, degd, hb, PN);
    gemm_kernel<192, false><<<ngb, 256, 0, stream>>>(hb, x, bn, wbl[2], proj, PN);
    gather_kernel<<<(PN + 3) / 4, 256, 0, stream>>>(proj, offu, idxu, degu, offd, idxd, degd, hb, PN);

    m1_kernel<<<192, 128, 0, stream>>>(P1, P2, tmpM);
    m2_kernel<<<192, 192, 0, stream>>>(tmpM, P1, M);
    decode_kernel<<<PB / 8, 192, 0, stream>>>(hb, di, M, out);
}

// Round 7
// 787.766 us; speedup vs baseline: 1.6136x; 1.0152x over previous
//
#include <hip/hip_runtime.h>

#define PN 50000
#define PE 1600000
#define PB 4096
#define NW 8
#define WSZ 6250
#define SCAP 250000   // staging capacity per partition (E/8 = 200K expected, 120 sigma slack)

typedef __attribute__((ext_vector_type(8))) short bf16x8;
typedef __attribute__((ext_vector_type(4))) float f32x4;

__device__ inline float b2f(ushort u) {
    union { unsigned int i; float f; } x; x.i = ((unsigned int)u) << 16; return x.f;
}
__device__ inline ushort f2b(float f) {
    union { float f; unsigned int i; } x; x.f = f;
    unsigned int r = (x.i + 0x7FFFu + ((x.i >> 16) & 1u)) >> 16;
    return (ushort)r;
}

// ---------------- workspace layout (in 4-byte words) ----------------
static constexpr size_t IDXCAP = PE + 7 * PN;                   // ushort entries (8-padded segments)
static constexpr size_t OFF_BN    = 0;                          // 256 f
static constexpr size_t OFF_TMPM  = 256;
static constexpr size_t OFF_M     = OFF_TMPM + 192 * 128;
static constexpr size_t OFF_DEGU  = OFF_M + 192 * 192;          // N int  -- zero block start
static constexpr size_t OFF_DEGD  = OFF_DEGU + PN;              // N int
static constexpr size_t OFF_CURU  = OFF_DEGD + PN;              // N int
static constexpr size_t OFF_CURD  = OFF_CURU + PN;              // N int
static constexpr size_t OFF_GCUR  = OFF_CURD + PN;              // 16 int -- zero block end
static constexpr size_t OFF_OFFU  = OFF_GCUR + 16;              // N+1 int
static constexpr size_t OFF_OFFD  = OFF_OFFU + PN + 1;          // N+1 int
static constexpr size_t OFF_IDXU  = ((OFF_OFFD + PN + 1 + 3) / 4) * 4;  // IDXCAP ushort
static constexpr size_t OFF_IDXD  = OFF_IDXU + (IDXCAP + 1) / 2;
static constexpr size_t OFF_STGU  = OFF_IDXD + (IDXCAP + 1) / 2;        // 8*SCAP u32
static constexpr size_t OFF_STGD  = OFF_STGU + 8 * (size_t)SCAP;
static constexpr size_t OFF_WB16  = OFF_STGD + 8 * (size_t)SCAP;        // 43008 words
static constexpr size_t OFF_HB    = OFF_WB16 + 43008;           // N*192 bf16
static constexpr size_t OFF_PROJ  = OFF_HB + (size_t)PN * 96;   // N*192 bf16

// ---------------- batchnorm stats ----------------
__global__ __launch_bounds__(256) void bn_stats_kernel(const float* __restrict__ x,
                                                       float* __restrict__ sums, int N) {
    __shared__ float ls[256], ls2[256];
    int col = threadIdx.x & 63;
    int rstart = blockIdx.x * 4 + (threadIdx.x >> 6);
    float s = 0.f, s2 = 0.f;
    for (int r = rstart; r < N; r += gridDim.x * 4) {
        float v = x[(size_t)r * 64 + col];
        s += v; s2 += v * v;
    }
    ls[threadIdx.x] = s; ls2[threadIdx.x] = s2;
    __syncthreads();
    if (threadIdx.x < 64) {
        s  = ls[threadIdx.x]  + ls[threadIdx.x + 64]  + ls[threadIdx.x + 128]  + ls[threadIdx.x + 192];
        s2 = ls2[threadIdx.x] + ls2[threadIdx.x + 64] + ls2[threadIdx.x + 128] + ls2[threadIdx.x + 192];
        atomicAdd(&sums[col], s);
        atomicAdd(&sums[64 + col], s2);
    }
}

__global__ __launch_bounds__(64) void bn_finalize_kernel(const float* __restrict__ gamma,
                                                         const float* __restrict__ beta,
                                                         float* __restrict__ bn, int N) {
    int c = threadIdx.x;
    float mean = bn[c] / (float)N;
    float var = bn[64 + c] / (float)N - mean * mean;
    float sc = gamma[c] * rsqrtf(var + 1e-5f);
    bn[128 + c] = sc;
    bn[192 + c] = beta[c] - mean * sc;
}

// ---------------- Pass A: edge binning (LDS buckets -> dense staging) + degree count --------
__global__ __launch_bounds__(256) void passA_kernel(const int* __restrict__ ei,
                                                    int* __restrict__ degu,
                                                    int* __restrict__ degd,
                                                    int* __restrict__ gcur,
                                                    uint* __restrict__ stgu,
                                                    uint* __restrict__ stgd, int E) {
    __shared__ uint sbuf[16][1024];     // 64 KB
    __shared__ int scnt[16], sbase[16];
    const int tid = threadIdx.x;
    for (int base = blockIdx.x * 1024; base < E; base += gridDim.x * 1024) {
        if (tid < 16) scnt[tid] = 0;
        __syncthreads();
#pragma unroll
        for (int j = 0; j < 4; ++j) {
            int e = base + j * 256 + tid;
            if (e < E) {
                int r = __builtin_nontemporal_load(&ei[e]);
                int c = __builtin_nontemporal_load(&ei[E + e]);
                int pu = c / WSZ;
                int slot = atomicAdd(&scnt[pu], 1);
                sbuf[pu][slot] = ((uint)c << 16) | (uint)r;
                atomicAdd(&degu[c], 1);
                int pd = r / WSZ;
                int slot2 = atomicAdd(&scnt[8 + pd], 1);
                sbuf[8 + pd][slot2] = ((uint)r << 16) | (uint)c;
                atomicAdd(&degd[r], 1);
            }
        }
        __syncthreads();
        if (tid < 16) sbase[tid] = atomicAdd(&gcur[tid], scnt[tid]);
        __syncthreads();
#pragma unroll 1
        for (int k = 0; k < 16; ++k) {
            int cnt = scnt[k];
            int gb = sbase[k];
            uint* dst = (k < 8) ? (stgu + (size_t)k * SCAP) : (stgd + (size_t)(k - 8) * SCAP);
            for (int i = tid; i < cnt; i += 256) {
                int gi = gb + i;
                if (gi < SCAP) dst[gi] = sbuf[k][i];
            }
        }
        __syncthreads();
    }
}

// exclusive scan of PADDED degrees ((d+7)&~7); 2 blocks, 4 elems/thread.
__global__ __launch_bounds__(1024) void scan_kernel(const int* __restrict__ degA,
                                                    const int* __restrict__ degB,
                                                    int* __restrict__ offA,
                                                    int* __restrict__ offB, int len) {
    const int* deg = blockIdx.x ? degB : degA;
    int* off = blockIdx.x ? offB : offA;
    __shared__ int wsum[17];
    int tid = threadIdx.x, lane = tid & 63, wid = tid >> 6;
    int run = 0;
    for (int base = 0; base < len; base += 4096) {
        int i4 = base + tid * 4;
        int4 v = make_int4(0, 0, 0, 0);
        if (i4 < len) v = *(const int4*)&deg[i4];
        v.x = (v.x + 7) & ~7; v.y = (v.y + 7) & ~7;
        v.z = (v.z + 7) & ~7; v.w = (v.w + 7) & ~7;
        int lsum = v.x + v.y + v.z + v.w;
        int inc = lsum;
#pragma unroll
        for (int d = 1; d < 64; d <<= 1) {
            int t = __shfl_up(inc, d);
            if (lane >= d) inc += t;
        }
        if (lane == 63) wsum[wid] = inc;
        __syncthreads();
        if (tid == 0) {
            int r2 = 0;
#pragma unroll
            for (int i = 0; i < 16; ++i) { int t = wsum[i]; wsum[i] = r2; r2 += t; }
            wsum[16] = r2;
        }
        __syncthreads();
        if (i4 < len) {
            int pre = run + wsum[wid] + inc - lsum;
            int4 o;
            o.x = pre; o.y = pre + v.x; o.z = o.y + v.y; o.w = o.z + v.z;
            *(int4*)&off[i4] = o;
        }
        run += wsum[16];
        __syncthreads();
    }
    if (tid == 0) off[len] = run;
}

// ---------------- Pass B: partition-local scatter (XCD-pinned) ----------------
__global__ __launch_bounds__(256) void passB_kernel(const uint* __restrict__ stgu,
                                                    const uint* __restrict__ stgd,
                                                    const int* __restrict__ gcur,
                                                    const int* __restrict__ offu,
                                                    const int* __restrict__ offd,
                                                    int* __restrict__ curu,
                                                    int* __restrict__ curd,
                                                    ushort* __restrict__ idxu,
                                                    ushort* __restrict__ idxd) {
    const int p = blockIdx.x & 7;
    const int g = blockIdx.x >> 3;
    const int G = gridDim.x >> 3;
    const int tid = threadIdx.x;
    {
        int cnt = min(gcur[p], SCAP);
        const uint* s = stgu + (size_t)p * SCAP;
        for (int i = g * 256 + tid; i < cnt; i += G * 256) {
            uint u = s[i];
            int dest = u >> 16, src = u & 0xFFFF;
            int pos = atomicAdd(&curu[dest], 1);
            idxu[offu[dest] + pos] = (ushort)src;
        }
    }
    {
        int cnt = min(gcur[8 + p], SCAP);
        const uint* s = stgd + (size_t)p * SCAP;
        for (int i = g * 256 + tid; i < cnt; i += G * 256) {
            uint u = s[i];
            int dest = u >> 16, src = u & 0xFFFF;
            int pos = atomicAdd(&curd[dest], 1);
            idxd[offd[dest] + pos] = (ushort)src;
        }
    }
}

// ---------------- weight convert ----------------
template<int K>
__global__ __launch_bounds__(256) void wconv_kernel(const float* __restrict__ Wu,
                                                    const float* __restrict__ Wd,
                                                    const float* __restrict__ Wb,
                                                    ushort* __restrict__ out) {
    int idx = blockIdx.x * 256 + threadIdx.x;
    if (idx >= 192 * K) return;
    int c = idx / K, k = idx - c * K;
    const float* W = (c < 64) ? Wu : (c < 128 ? Wd : Wb);
    out[idx] = f2b(W[k * 64 + (c & 63)]);
}

// ---------------- MFMA GEMM: proj[N,192] = A[N,K] @ W[K,192] ----------------
template<int K, bool BN>
__global__ __launch_bounds__(256) void gemm_kernel(const ushort* __restrict__ hb,
                                                   const float* __restrict__ x,
                                                   const float* __restrict__ bn,
                                                   const ushort* __restrict__ wb,
                                                   ushort* __restrict__ proj, int nrows) {
    constexpr int KP = K + 8;
    __shared__ ushort wlds[192 * KP];
    const int tid = threadIdx.x;
    constexpr int KB8 = K / 8;
    for (int idx = tid; idx < 192 * KB8; idx += 256) {
        int col = idx / KB8, kb = idx - col * KB8;
        *(bf16x8*)&wlds[col * KP + kb * 8] = *(const bf16x8*)&wb[(size_t)col * K + kb * 8];
    }
    __syncthreads();
    const int lane = tid & 63, wid = tid >> 6;
    const int kgrp = (lane >> 4) * 8;
    const int rbase = blockIdx.x * 128 + wid * 32;
    int ar[2] = { min(rbase + (lane & 15), nrows - 1),
                  min(rbase + 16 + (lane & 15), nrows - 1) };
    f32x4 acc[2][12];
#pragma unroll
    for (int rt = 0; rt < 2; ++rt)
#pragma unroll
        for (int ct = 0; ct < 12; ++ct) acc[rt][ct] = (f32x4)0.0f;

#pragma unroll
    for (int k0 = 0; k0 < K; k0 += 32) {
        bf16x8 af[2];
        if (BN) {
#pragma unroll
            for (int rt = 0; rt < 2; ++rt)
#pragma unroll
                for (int j = 0; j < 8; ++j) {
                    int c = k0 + kgrp + j;
                    float v = x[(size_t)ar[rt] * 64 + c] * bn[128 + c] + bn[192 + c];
                    af[rt][j] = (short)f2b(v);
                }
        } else {
#pragma unroll
            for (int rt = 0; rt < 2; ++rt)
                af[rt] = *(const bf16x8*)&hb[(size_t)ar[rt] * 192 + k0 + kgrp];
        }
#pragma unroll
        for (int ct = 0; ct < 12; ++ct) {
            bf16x8 bfr = *(const bf16x8*)&wlds[(ct * 16 + (lane & 15)) * KP + k0 + kgrp];
            acc[0][ct] = __builtin_amdgcn_mfma_f32_16x16x32_bf16(af[0], bfr, acc[0][ct], 0, 0, 0);
            acc[1][ct] = __builtin_amdgcn_mfma_f32_16x16x32_bf16(af[1], bfr, acc[1][ct], 0, 0, 0);
        }
    }
    const int orow0 = blockIdx.x * 128 + wid * 32 + (lane >> 4) * 4;
#pragma unroll
    for (int rt = 0; rt < 2; ++rt)
#pragma unroll
        for (int ct = 0; ct < 12; ++ct) {
            int ocol = ct * 16 + (lane & 15);
#pragma unroll
            for (int j = 0; j < 4; ++j) {
                int orow = orow0 + rt * 16 + j;
                if (orow < nrows) proj[(size_t)orow * 192 + ocol] = f2b(acc[rt][ct][j]);
            }
        }
}

// ---------------- fused gather + normalize + leaky (lane-split: 0-31 up, 32-63 dn) -------
// one wave per node; each lane loads u32 = 2 bf16 features; 1 VMEM op covers 2 rows.
__global__ __launch_bounds__(256) void gather_kernel(const ushort* __restrict__ proj,
                                                     const int* __restrict__ offu,
                                                     const ushort* __restrict__ idxu,
                                                     const int* __restrict__ degu,
                                                     const int* __restrict__ offd,
                                                     const ushort* __restrict__ idxd,
                                                     const int* __restrict__ degd,
                                                     ushort* __restrict__ hb, int N) {
    int n = blockIdx.x * 4 + (threadIdx.x >> 6);
    if (n >= N) return;
    const int lane = threadIdx.x & 63;
    const int half = lane >> 5;          // 0 = up, 1 = dn
    const int sl = lane & 31;            // feature pair index
    const int du = degu[n], dd = degd[n];
    const int d = half ? dd : du;
    const ushort* __restrict__ pidx = half ? (idxd + offd[n]) : (idxu + offu[n]);
    const uint* __restrict__ rowbase = (const uint*)proj + half * 32 + sl;
    float a0 = 0.f, a1 = 0.f;
    const int dmax = max(du, dd);
    for (int i = 0; i < dmax; i += 4) {
        ushort4 U = *(const ushort4*)(pidx + i);    // segments 8-padded: in-bounds
        int v0 = (i     < d), v1 = (i + 1 < d), v2 = (i + 2 < d), v3 = (i + 3 < d);
        int s0 = v0 ? (int)U.x : 0;
        int s1 = v1 ? (int)U.y : 0;
        int s2 = v2 ? (int)U.z : 0;
        int s3 = v3 ? (int)U.w : 0;
        uint w0 = rowbase[(size_t)s0 * 96];
        uint w1 = rowbase[(size_t)s1 * 96];
        uint w2 = rowbase[(size_t)s2 * 96];
        uint w3 = rowbase[(size_t)s3 * 96];
        if (!v0) w0 = 0; if (!v1) w1 = 0; if (!v2) w2 = 0; if (!v3) w3 = 0;
        a0 += __uint_as_float(w0 << 16) + __uint_as_float(w1 << 16)
            + __uint_as_float(w2 << 16) + __uint_as_float(w3 << 16);
        a1 += __uint_as_float(w0 & 0xFFFF0000u) + __uint_as_float(w1 & 0xFFFF0000u)
            + __uint_as_float(w2 & 0xFFFF0000u) + __uint_as_float(w3 & 0xFFFF0000u);
    }
    float scale = 1.0f / (float)max(d, 1);
    a0 *= scale; a1 *= scale;
    uint bw = (half == 0) ? ((const uint*)proj)[(size_t)n * 96 + 64 + sl] : 0u;
    float b0 = __uint_as_float(bw << 16);
    float b1 = __uint_as_float(bw & 0xFFFF0000u);
    float ss = a0 * a0 + a1 * a1 + b0 * b0 + b1 * b1;
#pragma unroll
    for (int off = 32; off; off >>= 1) ss += __shfl_xor(ss, off);
    float r = 1.0f / fmaxf(sqrtf(ss), 1e-12f);
    a0 *= r; a1 *= r; b0 *= r; b1 *= r;
    a0 = a0 >= 0.f ? a0 : 0.1f * a0;
    a1 = a1 >= 0.f ? a1 : 0.1f * a1;
    uint* hb32 = (uint*)hb;
    hb32[(size_t)n * 96 + half * 32 + sl] = (uint)f2b(a0) | ((uint)f2b(a1) << 16);
    if (half == 0) {
        b0 = b0 >= 0.f ? b0 : 0.1f * b0;
        b1 = b1 >= 0.f ? b1 : 0.1f * b1;
        hb32[(size_t)n * 96 + 64 + sl] = (uint)f2b(b0) | ((uint)f2b(b1) << 16);
    }
}

// ---------------- decoder ----------------
__global__ __launch_bounds__(128) void m1_kernel(const float* __restrict__ P1,
                                                 const float* __restrict__ P2,
                                                 float* __restrict__ tmpM) {
    int i = blockIdx.x, c = threadIdx.x;
    float s = 0.f;
    for (int k = 0; k < 128; ++k) s += P1[i * 128 + k] * P2[k * 128 + c];
    tmpM[i * 128 + c] = s;
}

__global__ __launch_bounds__(192) void m2_kernel(const float* __restrict__ tmpM,
                                                 const float* __restrict__ P1,
                                                 float* __restrict__ M) {
    __shared__ float trow[128];
    int i = blockIdx.x, j = threadIdx.x;
    if (j < 128) trow[j] = tmpM[i * 128 + j];
    __syncthreads();
    float s = 0.f;
    for (int k = 0; k < 128; ++k) s += trow[k] * P1[j * 128 + k];
    M[i * 192 + j] = s;
}

__global__ __launch_bounds__(192) void decode_kernel(const ushort* __restrict__ hb,
                                                     const int* __restrict__ di,
                                                     const float* __restrict__ M,
                                                     float* __restrict__ out) {
    __shared__ alignas(16) float bvs[8][192];
    __shared__ float red[3][8];
    int pb = blockIdx.x * 8;
    int i = threadIdx.x;
#pragma unroll
    for (int p = 0; p < 8; ++p) {
        int nb = di[(pb + p) * 2 + 1] - 1;
        bvs[p][i] = b2f(hb[(size_t)nb * 192 + i]);
    }
    __syncthreads();
    float t[8] = {};
    const float4* M4 = (const float4*)(M + (size_t)i * 192);
    for (int j4 = 0; j4 < 48; ++j4) {
        float4 m = M4[j4];
#pragma unroll
        for (int p = 0; p < 8; ++p) {
            float4 b = *(const float4*)&bvs[p][j4 * 4];
            t[p] += m.x * b.x + m.y * b.y + m.z * b.z + m.w * b.w;
        }
    }
    int wid = i >> 6, lane = i & 63;
#pragma unroll
    for (int p = 0; p < 8; ++p) {
        int na = di[(pb + p) * 2] - 1;
        float v = b2f(hb[(size_t)na * 192 + i]) * t[p];
#pragma unroll
        for (int off = 32; off; off >>= 1) v += __shfl_xor(v, off);
        if (lane == 0) red[wid][p] = v;
    }
    __syncthreads();
    if (i < 8) out[pb + i] = red[0][i] + red[1][i] + red[2][i];
}

extern "C" void kernel_launch(void* const* d_in, const int* in_sizes, int n_in,
                              void* d_out, int out_size, void* d_ws, size_t ws_size,
                              hipStream_t stream) {
    const float* x     = (const float*)d_in[0];
    const int*   ei    = (const int*)d_in[1];
    const int*   di    = (const int*)d_in[2];
    const float* gamma = (const float*)d_in[3];
    const float* beta  = (const float*)d_in[4];
    const float* Wu[3] = {(const float*)d_in[5], (const float*)d_in[8],  (const float*)d_in[11]};
    const float* Wd[3] = {(const float*)d_in[6], (const float*)d_in[9],  (const float*)d_in[12]};
    const float* Wb[3] = {(const float*)d_in[7], (const float*)d_in[10], (const float*)d_in[13]};
    const float* P1    = (const float*)d_in[14];
    const float* P2    = (const float*)d_in[15];
    float* out = (float*)d_out;
    float* ws  = (float*)d_ws;

    float* bn    = ws + OFF_BN;
    float* tmpM  = ws + OFF_TMPM;
    float* M     = ws + OFF_M;
    int* degu = (int*)(ws + OFF_DEGU);
    int* degd = (int*)(ws + OFF_DEGD);
    int* curu = (int*)(ws + OFF_CURU);
    int* curd = (int*)(ws + OFF_CURD);
    int* gcur = (int*)(ws + OFF_GCUR);
    int* offu = (int*)(ws + OFF_OFFU);
    int* offd = (int*)(ws + OFF_OFFD);
    ushort* idxu = (ushort*)(ws + OFF_IDXU);
    ushort* idxd = (ushort*)(ws + OFF_IDXD);
    uint* stgu = (uint*)(ws + OFF_STGU);
    uint* stgd = (uint*)(ws + OFF_STGD);
    ushort* wb16 = (ushort*)(ws + OFF_WB16);
    ushort* hb   = (ushort*)(ws + OFF_HB);
    ushort* proj = (ushort*)(ws + OFF_PROJ);
    ushort* wbl[3] = {wb16, wb16 + 12288, wb16 + 49152};

    hipMemsetAsync(bn, 0, 128 * sizeof(float), stream);
    hipMemsetAsync(degu, 0, (4 * (size_t)PN + 16) * sizeof(int), stream);  // degu|degd|curu|curd|gcur

    bn_stats_kernel<<<200, 256, 0, stream>>>(x, bn, PN);
    bn_finalize_kernel<<<1, 64, 0, stream>>>(gamma, beta, bn, PN);

    passA_kernel<<<512, 256, 0, stream>>>(ei, degu, degd, gcur, stgu, stgd, PE);
    scan_kernel<<<2, 1024, 0, stream>>>(degu, degd, offu, offd, PN);
    passB_kernel<<<512, 256, 0, stream>>>(stgu, stgd, gcur, offu, offd, curu, curd, idxu, idxd);

    wconv_kernel<64><<<(192 * 64 + 255) / 256, 256, 0, stream>>>(Wu[0], Wd[0], Wb[0], wbl[0]);
    wconv_kernel<192><<<(192 * 192 + 255) / 256, 256, 0, stream>>>(Wu[1], Wd[1], Wb[1], wbl[1]);
    wconv_kernel<192><<<(192 * 192 + 255) / 256, 256, 0, stream>>>(Wu[2], Wd[2], Wb[2], wbl[2]);

    const int ngb = (PN + 127) / 128;
    gemm_kernel<64, true><<<ngb, 256, 0, stream>>>(hb, x, bn, wbl[0], proj, PN);
    gather_kernel<<<(PN + 3) / 4, 256, 0, stream>>>(proj, offu, idxu, degu, offd, idxd, degd, hb, PN);
    gemm_kernel<192, false><<<ngb, 256, 0, stream>>>(hb, x, bn, wbl[1], proj, PN);
    gather_kernel<<<(PN + 3) / 4, 256, 0, stream>>>(proj, offu, idxu, degu, offd, idxd, degd, hb, PN);
    gemm_kernel<192, false><<<ngb, 256, 0, stream>>>(hb, x, bn, wbl[2], proj, PN);
    gather_kernel<<<(PN + 3) / 4, 256, 0, stream>>>(proj, offu, idxu, degu, offd, idxd, degd, hb, PN);

    m1_kernel<<<192, 128, 0, stream>>>(P1, P2, tmpM);
    m2_kernel<<<192, 192, 0, stream>>>(tmpM, P1, M);
    decode_kernel<<<PB / 8, 192, 0, stream>>>(hb, di, M, out);
}

// Round 8
// 637.085 us; speedup vs baseline: 1.9953x; 1.2365x over previous
//
#include <hip/hip_runtime.h>

#define PN 50000
#define PE 1600000
#define PB 4096
#define NW 8
#define WSZ 6250
#define SCAP 250000   // staging capacity per partition (E/8 = 200K expected)
#define NSL 8         // slices per partition for hist/scatter

typedef __attribute__((ext_vector_type(8))) short bf16x8;
typedef __attribute__((ext_vector_type(4))) float f32x4;

__device__ inline float b2f(ushort u) {
    union { unsigned int i; float f; } x; x.i = ((unsigned int)u) << 16; return x.f;
}
__device__ inline ushort f2b(float f) {
    union { float f; unsigned int i; } x; x.f = f;
    unsigned int r = (x.i + 0x7FFFu + ((x.i >> 16) & 1u)) >> 16;
    return (ushort)r;
}

// ---------------- workspace layout (in 4-byte words) ----------------
static constexpr size_t IDXCAP2 = PE + 7 * (size_t)PN + 1024;   // ushort entries (+ tail guard)
static constexpr size_t OFF_BN     = 0;                          // 256 f
static constexpr size_t OFF_GCUR   = 256;                        // 16 int (zeroed with BN)
static constexpr size_t OFF_TMPM   = 272;                        // 192*128
static constexpr size_t OFF_M      = OFF_TMPM + 192 * 128;       // 192*192
static constexpr size_t OFF_DEGU   = OFF_M + 192 * 192;          // N int (scan-written, dense)
static constexpr size_t OFF_DEGD   = OFF_DEGU + PN;              // N int
static constexpr size_t OFF_OFFU   = OFF_DEGD + PN;              // N+4 int
static constexpr size_t OFF_OFFD   = OFF_OFFU + PN + 4;          // N+4 int
static constexpr size_t OFF_PHISTU = OFF_OFFD + PN + 4;          // NSL*N int
static constexpr size_t OFF_PHISTD = OFF_PHISTU + NSL * (size_t)PN;
static constexpr size_t OFF_IDXU   = OFF_PHISTD + NSL * (size_t)PN;   // IDXCAP2 ushort
static constexpr size_t OFF_IDXD   = OFF_IDXU + (IDXCAP2 + 1) / 2;
static constexpr size_t OFF_STGU   = OFF_IDXD + (IDXCAP2 + 1) / 2;    // 8*SCAP u32
static constexpr size_t OFF_STGD   = OFF_STGU + 8 * (size_t)SCAP;
static constexpr size_t OFF_WB16   = OFF_STGD + 8 * (size_t)SCAP;     // 43008 words
static constexpr size_t OFF_HB     = OFF_WB16 + 43008;           // N*192 bf16
static constexpr size_t OFF_PROJ   = OFF_HB + (size_t)PN * 96;   // N*192 bf16

// ---------------- batchnorm stats ----------------
__global__ __launch_bounds__(256) void bn_stats_kernel(const float* __restrict__ x,
                                                       float* __restrict__ sums, int N) {
    __shared__ float ls[256], ls2[256];
    int col = threadIdx.x & 63;
    int rstart = blockIdx.x * 4 + (threadIdx.x >> 6);
    float s = 0.f, s2 = 0.f;
    for (int r = rstart; r < N; r += gridDim.x * 4) {
        float v = x[(size_t)r * 64 + col];
        s += v; s2 += v * v;
    }
    ls[threadIdx.x] = s; ls2[threadIdx.x] = s2;
    __syncthreads();
    if (threadIdx.x < 64) {
        s  = ls[threadIdx.x]  + ls[threadIdx.x + 64]  + ls[threadIdx.x + 128]  + ls[threadIdx.x + 192];
        s2 = ls2[threadIdx.x] + ls2[threadIdx.x + 64] + ls2[threadIdx.x + 128] + ls2[threadIdx.x + 192];
        atomicAdd(&sums[col], s);
        atomicAdd(&sums[64 + col], s2);
    }
}

__global__ __launch_bounds__(64) void bn_finalize_kernel(const float* __restrict__ gamma,
                                                         const float* __restrict__ beta,
                                                         float* __restrict__ bn, int N) {
    int c = threadIdx.x;
    float mean = bn[c] / (float)N;
    float var = bn[64 + c] / (float)N - mean * mean;
    float sc = gamma[c] * rsqrtf(var + 1e-5f);
    bn[128 + c] = sc;
    bn[192 + c] = beta[c] - mean * sc;
}

// ---------------- CSR1: edge binning (LDS buckets -> dense staging), NO node atomics ------
__global__ __launch_bounds__(256) void bin_kernel(const int* __restrict__ ei,
                                                  int* __restrict__ gcur,
                                                  uint* __restrict__ stgu,
                                                  uint* __restrict__ stgd, int E) {
    __shared__ uint sbuf[16][1024];     // 64 KB
    __shared__ int scnt[16], sbase[16];
    const int tid = threadIdx.x;
    for (int base = blockIdx.x * 1024; base < E; base += gridDim.x * 1024) {
        if (tid < 16) scnt[tid] = 0;
        __syncthreads();
#pragma unroll
        for (int j = 0; j < 4; ++j) {
            int e = base + j * 256 + tid;
            if (e < E) {
                int r = __builtin_nontemporal_load(&ei[e]);
                int c = __builtin_nontemporal_load(&ei[E + e]);
                int pu = c / WSZ;
                int slot = atomicAdd(&scnt[pu], 1);
                sbuf[pu][slot] = ((uint)c << 16) | (uint)r;
                int pd = r / WSZ;
                int slot2 = atomicAdd(&scnt[8 + pd], 1);
                sbuf[8 + pd][slot2] = ((uint)r << 16) | (uint)c;
            }
        }
        __syncthreads();
        if (tid < 16) sbase[tid] = atomicAdd(&gcur[tid], scnt[tid]);
        __syncthreads();
#pragma unroll 1
        for (int k = 0; k < 16; ++k) {
            int cnt = scnt[k];
            int gb = sbase[k];
            uint* dst = (k < 8) ? (stgu + (size_t)k * SCAP) : (stgd + (size_t)(k - 8) * SCAP);
            for (int i = tid; i < cnt; i += 256) {
                int gi = gb + i;
                if (gi < SCAP) dst[gi] = sbuf[k][i];
            }
        }
        __syncthreads();
    }
}

// ---------------- CSR2: per-(partition,slice) histogram via LDS atomics ----------------
// grid 128: p = blk&7 (XCD-pinned), dir = (blk>>3)&1, s = blk>>4
__global__ __launch_bounds__(256) void hist_kernel(const uint* __restrict__ stgu,
                                                   const uint* __restrict__ stgd,
                                                   const int* __restrict__ gcur,
                                                   int* __restrict__ phistu,
                                                   int* __restrict__ phistd) {
    __shared__ int hist[WSZ];
    const int p = blockIdx.x & 7;
    const int dir = (blockIdx.x >> 3) & 1;
    const int s = blockIdx.x >> 4;
    const int tid = threadIdx.x;
    const int lo = p * WSZ;
    for (int i = tid; i < WSZ; i += 256) hist[i] = 0;
    __syncthreads();
    const int cnt = min(gcur[dir * 8 + p], SCAP);
    const uint* stg = (dir ? stgd : stgu) + (size_t)p * SCAP;
    const int per = (cnt + NSL - 1) / NSL;
    const int s0 = s * per, s1 = min(cnt, s0 + per);
    for (int i = s0 + tid; i < s1; i += 256)
        atomicAdd(&hist[(int)(stg[i] >> 16) - lo], 1);
    __syncthreads();
    int* ph = (dir ? phistd : phistu) + (size_t)s * PN + lo;
    for (int i = tid; i < WSZ; i += 256) ph[i] = hist[i];
}

// ---------------- scan: deg = sum slices; pad to 8; exclusive scan ----------------
__global__ __launch_bounds__(1024) void scan_kernel(const int* __restrict__ phA,
                                                    const int* __restrict__ phB,
                                                    int* __restrict__ offA,
                                                    int* __restrict__ offB,
                                                    int* __restrict__ degA,
                                                    int* __restrict__ degB, int len) {
    const int* ph = blockIdx.x ? phB : phA;
    int* off = blockIdx.x ? offB : offA;
    int* dego = blockIdx.x ? degB : degA;
    __shared__ int wsum[17];
    int tid = threadIdx.x, lane = tid & 63, wid = tid >> 6;
    int run = 0;
    for (int base = 0; base < len; base += 4096) {
        int i4 = base + tid * 4;
        int4 v = make_int4(0, 0, 0, 0);
        if (i4 < len) {
#pragma unroll
            for (int sl = 0; sl < NSL; ++sl) {
                int4 t = *(const int4*)&ph[(size_t)sl * len + i4];
                v.x += t.x; v.y += t.y; v.z += t.z; v.w += t.w;
            }
            *(int4*)&dego[i4] = v;
        }
        v.x = (v.x + 7) & ~7; v.y = (v.y + 7) & ~7;
        v.z = (v.z + 7) & ~7; v.w = (v.w + 7) & ~7;
        int lsum = v.x + v.y + v.z + v.w;
        int inc = lsum;
#pragma unroll
        for (int d = 1; d < 64; d <<= 1) {
            int t = __shfl_up(inc, d);
            if (lane >= d) inc += t;
        }
        if (lane == 63) wsum[wid] = inc;
        __syncthreads();
        if (tid == 0) {
            int r2 = 0;
#pragma unroll
            for (int i = 0; i < 16; ++i) { int t = wsum[i]; wsum[i] = r2; r2 += t; }
            wsum[16] = r2;
        }
        __syncthreads();
        if (i4 < len) {
            int pre = run + wsum[wid] + inc - lsum;
            int4 o;
            o.x = pre; o.y = pre + v.x; o.z = o.y + v.y; o.w = o.z + v.z;
            *(int4*)&off[i4] = o;
        }
        run += wsum[16];
        __syncthreads();
    }
    if (tid == 0) off[len] = run;
}

// ---------------- CSR3: per-(partition,slice) scatter with LDS cursors ----------------
__global__ __launch_bounds__(256) void scatter_kernel(const uint* __restrict__ stgu,
                                                      const uint* __restrict__ stgd,
                                                      const int* __restrict__ gcur,
                                                      const int* __restrict__ phistu,
                                                      const int* __restrict__ phistd,
                                                      const int* __restrict__ offu,
                                                      const int* __restrict__ offd,
                                                      ushort* __restrict__ idxu,
                                                      ushort* __restrict__ idxd) {
    __shared__ int cur[WSZ];
    const int p = blockIdx.x & 7;
    const int dir = (blockIdx.x >> 3) & 1;
    const int s = blockIdx.x >> 4;
    const int tid = threadIdx.x;
    const int lo = p * WSZ;
    const int* off = (dir ? offd : offu);
    const int* phist = (dir ? phistd : phistu);
    for (int i = tid; i < WSZ; i += 256) {
        int c = off[lo + i];
        for (int t = 0; t < s; ++t) c += phist[(size_t)t * PN + lo + i];
        cur[i] = c;
    }
    __syncthreads();
    const int cnt = min(gcur[dir * 8 + p], SCAP);
    const uint* stg = (dir ? stgd : stgu) + (size_t)p * SCAP;
    ushort* idx = (dir ? idxd : idxu);
    const int per = (cnt + NSL - 1) / NSL;
    const int s0 = s * per, s1 = min(cnt, s0 + per);
    for (int i = s0 + tid; i < s1; i += 256) {
        uint u = stg[i];
        int pos = atomicAdd(&cur[(int)(u >> 16) - lo], 1);
        idx[pos] = (ushort)(u & 0xFFFFu);
    }
}

// ---------------- weight convert ----------------
template<int K>
__global__ __launch_bounds__(256) void wconv_kernel(const float* __restrict__ Wu,
                                                    const float* __restrict__ Wd,
                                                    const float* __restrict__ Wb,
                                                    ushort* __restrict__ out) {
    int idx = blockIdx.x * 256 + threadIdx.x;
    if (idx >= 192 * K) return;
    int c = idx / K, k = idx - c * K;
    const float* W = (c < 64) ? Wu : (c < 128 ? Wd : Wb);
    out[idx] = f2b(W[k * 64 + (c & 63)]);
}

// ---------------- MFMA GEMM: proj[N,192] = A[N,K] @ W[K,192] ----------------
template<int K, bool BN>
__global__ __launch_bounds__(256) void gemm_kernel(const ushort* __restrict__ hb,
                                                   const float* __restrict__ x,
                                                   const float* __restrict__ bn,
                                                   const ushort* __restrict__ wb,
                                                   ushort* __restrict__ proj, int nrows) {
    constexpr int KP = K + 8;
    __shared__ ushort wlds[192 * KP];
    const int tid = threadIdx.x;
    constexpr int KB8 = K / 8;
    for (int idx = tid; idx < 192 * KB8; idx += 256) {
        int col = idx / KB8, kb = idx - col * KB8;
        *(bf16x8*)&wlds[col * KP + kb * 8] = *(const bf16x8*)&wb[(size_t)col * K + kb * 8];
    }
    __syncthreads();
    const int lane = tid & 63, wid = tid >> 6;
    const int kgrp = (lane >> 4) * 8;
    const int rbase = blockIdx.x * 128 + wid * 32;
    int ar[2] = { min(rbase + (lane & 15), nrows - 1),
                  min(rbase + 16 + (lane & 15), nrows - 1) };
    f32x4 acc[2][12];
#pragma unroll
    for (int rt = 0; rt < 2; ++rt)
#pragma unroll
        for (int ct = 0; ct < 12; ++ct) acc[rt][ct] = (f32x4)0.0f;

#pragma unroll
    for (int k0 = 0; k0 < K; k0 += 32) {
        bf16x8 af[2];
        if (BN) {
#pragma unroll
            for (int rt = 0; rt < 2; ++rt)
#pragma unroll
                for (int j = 0; j < 8; ++j) {
                    int c = k0 + kgrp + j;
                    float v = x[(size_t)ar[rt] * 64 + c] * bn[128 + c] + bn[192 + c];
                    af[rt][j] = (short)f2b(v);
                }
        } else {
#pragma unroll
            for (int rt = 0; rt < 2; ++rt)
                af[rt] = *(const bf16x8*)&hb[(size_t)ar[rt] * 192 + k0 + kgrp];
        }
#pragma unroll
        for (int ct = 0; ct < 12; ++ct) {
            bf16x8 bfr = *(const bf16x8*)&wlds[(ct * 16 + (lane & 15)) * KP + k0 + kgrp];
            acc[0][ct] = __builtin_amdgcn_mfma_f32_16x16x32_bf16(af[0], bfr, acc[0][ct], 0, 0, 0);
            acc[1][ct] = __builtin_amdgcn_mfma_f32_16x16x32_bf16(af[1], bfr, acc[1][ct], 0, 0, 0);
        }
    }
    const int orow0 = blockIdx.x * 128 + wid * 32 + (lane >> 4) * 4;
#pragma unroll
    for (int rt = 0; rt < 2; ++rt)
#pragma unroll
        for (int ct = 0; ct < 12; ++ct) {
            int ocol = ct * 16 + (lane & 15);
#pragma unroll
            for (int j = 0; j < 4; ++j) {
                int orow = orow0 + rt * 16 + j;
                if (orow < nrows) proj[(size_t)orow * 192 + ocol] = f2b(acc[rt][ct][j]);
            }
        }
}

// ---------------- fused gather + normalize + leaky (lane-split: 0-31 up, 32-63 dn) -------
__global__ __launch_bounds__(256) void gather_kernel(const ushort* __restrict__ proj,
                                                     const int* __restrict__ offu,
                                                     const ushort* __restrict__ idxu,
                                                     const int* __restrict__ degu,
                                                     const int* __restrict__ offd,
                                                     const ushort* __restrict__ idxd,
                                                     const int* __restrict__ degd,
                                                     ushort* __restrict__ hb, int N) {
    int n = blockIdx.x * 4 + (threadIdx.x >> 6);
    if (n >= N) return;
    const int lane = threadIdx.x & 63;
    const int half = lane >> 5;          // 0 = up, 1 = dn
    const int sl = lane & 31;            // feature pair index
    const int du = degu[n], dd = degd[n];
    const int d = half ? dd : du;
    const ushort* __restrict__ pidx = half ? (idxd + offd[n]) : (idxu + offu[n]);
    const uint* __restrict__ rowbase = (const uint*)proj + half * 32 + sl;
    float a0 = 0.f, a1 = 0.f;
    const int dmax = max(du, dd);
    for (int i = 0; i < dmax; i += 4) {
        ushort4 U = *(const ushort4*)(pidx + i);    // segments 8-padded: in-bounds
        int v0 = (i     < d), v1 = (i + 1 < d), v2 = (i + 2 < d), v3 = (i + 3 < d);
        int s0 = v0 ? (int)U.x : 0;
        int s1 = v1 ? (int)U.y : 0;
        int s2 = v2 ? (int)U.z : 0;
        int s3 = v3 ? (int)U.w : 0;
        uint w0 = rowbase[(size_t)s0 * 96];
        uint w1 = rowbase[(size_t)s1 * 96];
        uint w2 = rowbase[(size_t)s2 * 96];
        uint w3 = rowbase[(size_t)s3 * 96];
        if (!v0) w0 = 0; if (!v1) w1 = 0; if (!v2) w2 = 0; if (!v3) w3 = 0;
        a0 += __uint_as_float(w0 << 16) + __uint_as_float(w1 << 16)
            + __uint_as_float(w2 << 16) + __uint_as_float(w3 << 16);
        a1 += __uint_as_float(w0 & 0xFFFF0000u) + __uint_as_float(w1 & 0xFFFF0000u)
            + __uint_as_float(w2 & 0xFFFF0000u) + __uint_as_float(w3 & 0xFFFF0000u);
    }
    float scale = 1.0f / (float)max(d, 1);
    a0 *= scale; a1 *= scale;
    uint bw = (half == 0) ? ((const uint*)proj)[(size_t)n * 96 + 64 + sl] : 0u;
    float b0 = __uint_as_float(bw << 16);
    float b1 = __uint_as_float(bw & 0xFFFF0000u);
    float ss = a0 * a0 + a1 * a1 + b0 * b0 + b1 * b1;
#pragma unroll
    for (int off = 32; off; off >>= 1) ss += __shfl_xor(ss, off);
    float r = 1.0f / fmaxf(sqrtf(ss), 1e-12f);
    a0 *= r; a1 *= r; b0 *= r; b1 *= r;
    a0 = a0 >= 0.f ? a0 : 0.1f * a0;
    a1 = a1 >= 0.f ? a1 : 0.1f * a1;
    uint* hb32 = (uint*)hb;
    hb32[(size_t)n * 96 + half * 32 + sl] = (uint)f2b(a0) | ((uint)f2b(a1) << 16);
    if (half == 0) {
        b0 = b0 >= 0.f ? b0 : 0.1f * b0;
        b1 = b1 >= 0.f ? b1 : 0.1f * b1;
        hb32[(size_t)n * 96 + 64 + sl] = (uint)f2b(b0) | ((uint)f2b(b1) << 16);
    }
}

// ---------------- decoder ----------------
__global__ __launch_bounds__(128) void m1_kernel(const float* __restrict__ P1,
                                                 const float* __restrict__ P2,
                                                 float* __restrict__ tmpM) {
    int i = blockIdx.x, c = threadIdx.x;
    float s = 0.f;
    for (int k = 0; k < 128; ++k) s += P1[i * 128 + k] * P2[k * 128 + c];
    tmpM[i * 128 + c] = s;
}

__global__ __launch_bounds__(192) void m2_kernel(const float* __restrict__ tmpM,
                                                 const float* __restrict__ P1,
                                                 float* __restrict__ M) {
    __shared__ float trow[128];
    int i = blockIdx.x, j = threadIdx.x;
    if (j < 128) trow[j] = tmpM[i * 128 + j];
    __syncthreads();
    float s = 0.f;
    for (int k = 0; k < 128; ++k) s += trow[k] * P1[j * 128 + k];
    M[i * 192 + j] = s;
}

__global__ __launch_bounds__(192) void decode_kernel(const ushort* __restrict__ hb,
                                                     const int* __restrict__ di,
                                                     const float* __restrict__ M,
                                                     float* __restrict__ out) {
    __shared__ alignas(16) float bvs[8][192];
    __shared__ float red[3][8];
    int pb = blockIdx.x * 8;
    int i = threadIdx.x;
#pragma unroll
    for (int p = 0; p < 8; ++p) {
        int nb = di[(pb + p) * 2 + 1] - 1;
        bvs[p][i] = b2f(hb[(size_t)nb * 192 + i]);
    }
    __syncthreads();
    float t[8] = {};
    const float4* M4 = (const float4*)(M + (size_t)i * 192);
    for (int j4 = 0; j4 < 48; ++j4) {
        float4 m = M4[j4];
#pragma unroll
        for (int p = 0; p < 8; ++p) {
            float4 b = *(const float4*)&bvs[p][j4 * 4];
            t[p] += m.x * b.x + m.y * b.y + m.z * b.z + m.w * b.w;
        }
    }
    int wid = i >> 6, lane = i & 63;
#pragma unroll
    for (int p = 0; p < 8; ++p) {
        int na = di[(pb + p) * 2] - 1;
        float v = b2f(hb[(size_t)na * 192 + i]) * t[p];
#pragma unroll
        for (int off = 32; off; off >>= 1) v += __shfl_xor(v, off);
        if (lane == 0) red[wid][p] = v;
    }
    __syncthreads();
    if (i < 8) out[pb + i] = red[0][i] + red[1][i] + red[2][i];
}

extern "C" void kernel_launch(void* const* d_in, const int* in_sizes, int n_in,
                              void* d_out, int out_size, void* d_ws, size_t ws_size,
                              hipStream_t stream) {
    const float* x     = (const float*)d_in[0];
    const int*   ei    = (const int*)d_in[1];
    const int*   di    = (const int*)d_in[2];
    const float* gamma = (const float*)d_in[3];
    const float* beta  = (const float*)d_in[4];
    const float* Wu[3] = {(const float*)d_in[5], (const float*)d_in[8],  (const float*)d_in[11]};
    const float* Wd[3] = {(const float*)d_in[6], (const float*)d_in[9],  (const float*)d_in[12]};
    const float* Wb[3] = {(const float*)d_in[7], (const float*)d_in[10], (const float*)d_in[13]};
    const float* P1    = (const float*)d_in[14];
    const float* P2    = (const float*)d_in[15];
    float* out = (float*)d_out;
    float* ws  = (float*)d_ws;

    float* bn    = ws + OFF_BN;
    int* gcur  = (int*)(ws + OFF_GCUR);
    float* tmpM  = ws + OFF_TMPM;
    float* M     = ws + OFF_M;
    int* degu  = (int*)(ws + OFF_DEGU);
    int* degd  = (int*)(ws + OFF_DEGD);
    int* offu  = (int*)(ws + OFF_OFFU);
    int* offd  = (int*)(ws + OFF_OFFD);
    int* phistu = (int*)(ws + OFF_PHISTU);
    int* phistd = (int*)(ws + OFF_PHISTD);
    ushort* idxu = (ushort*)(ws + OFF_IDXU);
    ushort* idxd = (ushort*)(ws + OFF_IDXD);
    uint* stgu = (uint*)(ws + OFF_STGU);
    uint* stgd = (uint*)(ws + OFF_STGD);
    ushort* wb16 = (ushort*)(ws + OFF_WB16);
    ushort* hb   = (ushort*)(ws + OFF_HB);
    ushort* proj = (ushort*)(ws + OFF_PROJ);
    ushort* wbl[3] = {wb16, wb16 + 12288, wb16 + 49152};

    hipMemsetAsync(ws, 0, 272 * sizeof(float), stream);   // bn sums + gcur

    bn_stats_kernel<<<200, 256, 0, stream>>>(x, bn, PN);
    bn_finalize_kernel<<<1, 64, 0, stream>>>(gamma, beta, bn, PN);

    bin_kernel<<<512, 256, 0, stream>>>(ei, gcur, stgu, stgd, PE);
    hist_kernel<<<16 * NSL, 256, 0, stream>>>(stgu, stgd, gcur, phistu, phistd);
    scan_kernel<<<2, 1024, 0, stream>>>(phistu, phistd, offu, offd, degu, degd, PN);
    scatter_kernel<<<16 * NSL, 256, 0, stream>>>(stgu, stgd, gcur, phistu, phistd,
                                                 offu, offd, idxu, idxd);

    wconv_kernel<64><<<(192 * 64 + 255) / 256, 256, 0, stream>>>(Wu[0], Wd[0], Wb[0], wbl[0]);
    wconv_kernel<192><<<(192 * 192 + 255) / 256, 256, 0, stream>>>(Wu[1], Wd[1], Wb[1], wbl[1]);
    wconv_kernel<192><<<(192 * 192 + 255) / 256, 256, 0, stream>>>(Wu[2], Wd[2], Wb[2], wbl[2]);

    const int ngb = (PN + 127) / 128;
    gemm_kernel<64, true><<<ngb, 256, 0, stream>>>(hb, x, bn, wbl[0], proj, PN);
    gather_kernel<<<(PN + 3) / 4, 256, 0, stream>>>(proj, offu, idxu, degu, offd, idxd, degd, hb, PN);
    gemm_kernel<192, false><<<ngb, 256, 0, stream>>>(hb, x, bn, wbl[1], proj, PN);
    gather_kernel<<<(PN + 3) / 4, 256, 0, stream>>>(proj, offu, idxu, degu, offd, idxd, degd, hb, PN);
    gemm_kernel<192, false><<<ngb, 256, 0, stream>>>(hb, x, bn, wbl[2], proj, PN);
    gather_kernel<<<(PN + 3) / 4, 256, 0, stream>>>(proj, offu, idxu, degu, offd, idxd, degd, hb, PN);

    m1_kernel<<<192, 128, 0, stream>>>(P1, P2, tmpM);
    m2_kernel<<<192, 192, 0, stream>>>(tmpM, P1, M);
    decode_kernel<<<PB / 8, 192, 0, stream>>>(hb, di, M, out);
}